// Round 9
// baseline (484.475 us; speedup 1.0000x reference)
//
#include <hip/hip_runtime.h>
#include <hip/hip_bf16.h>
#include <math.h>

#define N 8192
#define EPSV 1e-05f
#define NSPLIT 32
#define CPS (N / NSPLIT)    // 256 columns per split
#define NSTEP (CPS / 32)    // 8 steps of 32 cols

typedef short bf16x8 __attribute__((ext_vector_type(8)));
typedef float f32x4 __attribute__((ext_vector_type(4)));
typedef float f32x16 __attribute__((ext_vector_type(16)));
typedef unsigned short u16;
typedef unsigned int u32;

// ---- float workspace layout ----
#define WS_SCAL 0
#define WS_H    64                        // N*64 fp32
#define WS_ST   (WS_H + N * 64)           // N
#define WS_SBI  (WS_ST + N)               // N
#define WS_DEN  (WS_SBI + N)              // N      (atomic-accumulated)
#define WS_AGG  (WS_DEN + N)              // N*64   (atomic-accumulated, 2 MB: LLC-resident)
#define WS_F_END (WS_AGG + N * 64)
// ---- u16 (bf16) region, offsets in u16 units from (u16*)ws ----
#define WU_BASE (WS_F_END * 2)
#define WU_QB (WU_BASE)                   // N*64 row-major (q, pre-scaled)
#define WU_KB (WU_BASE + N * 64)          // N*64 row-major
#define WU_MB (WU_BASE + 2 * N * 64)      // N*64 row-major (messages)
// fragment-packed arrays (pack_k output): MFMA operands as contiguous 1KB frags
#define WU_QP (WU_BASE + 3 * N * 64)      // (N/32)*5*64*8 = 655360 u16
#define WU_KP (WU_QP + (N / 32) * 5 * 64 * 8)
#define WU_MP (WU_KP + (N / 32) * 5 * 64 * 8)   // (N/32)*4*64*8 = 524288 u16

static __device__ __forceinline__ u16 f2bf(float f) {
    __hip_bfloat16 h = __float2bfloat16(f);
    return *(u16*)&h;
}
static __device__ __forceinline__ u32 pk2(float a, float b) {
    return (u32)f2bf(a) | ((u32)f2bf(b) << 16);
}
static __device__ __forceinline__ bf16x8 mk8(u32 a, u32 b, u32 c, u32 d) {
    union { u32 u[4]; bf16x8 v; } x;
    x.u[0] = a; x.u[1] = b; x.u[2] = c; x.u[3] = d;
    return x.v;
}

// ---------------- Kernel A: scalar prep ----------------
__global__ void prep_k(const float* __restrict__ tc, const float* __restrict__ wg,
                       const float* __restrict__ bg, const float* __restrict__ sbias,
                       float* __restrict__ scal) {
    int j = threadIdx.x;  // 64 threads
    float v = tc[0] * wg[j] + tc[1] * wg[64 + j] + bg[j];
    float g = 1.0f / (1.0f + __expf(-v));
    for (int off = 32; off; off >>= 1) g += __shfl_xor(g, off, 64);
    if (j == 0) {
        scal[0] = 0.125f * (g * (1.0f / 64.0f));   // qscale (gate mean + 1/sqrt(64) folded)
        scal[1] = sbias[0] * (1.0f - tc[0]);        // coef
    }
}

// ---------------- Kernel B: embed (h fp32; q,k,m bf16; st, sbi) ----------------
// Also zero-inits the atomic accumulation buffers (agg, den) for its rows.
__global__ __launch_bounds__(256) void embed_k(
    const float* __restrict__ nf, const float* __restrict__ tc,
    const float* __restrict__ w1, const float* __restrict__ b1,
    const float* __restrict__ w2, const float* __restrict__ b2,
    const float* __restrict__ wq, const float* __restrict__ bq,
    const float* __restrict__ wk, const float* __restrict__ bk,
    const float* __restrict__ wm, const float* __restrict__ bm,
    float* __restrict__ ws)
{
    const int w = threadIdx.x >> 6, lane = threadIdx.x & 63;
    const int row = blockIdx.x * 4 + w;
    __shared__ float ts[4][64], hs[4][64];
    const float qscale = ws[WS_SCAL + 0];
    const float coef   = ws[WS_SCAL + 1];
    const float f0 = nf[row * 3], f1 = nf[row * 3 + 1], f2 = nf[row * 3 + 2];
    const float t0 = tc[0], t1 = tc[1];
    ws[WS_AGG + (size_t)row * 64 + lane] = 0.0f;    // zero atomic target
    float v = b1[lane];
    v = fmaf(f0, w1[lane], v);
    v = fmaf(f1, w1[64 + lane], v);
    v = fmaf(f2, w1[128 + lane], v);
    v = fmaf(t0, w1[192 + lane], v);
    v = fmaf(t1, w1[256 + lane], v);
    ts[w][lane] = fmaxf(v, 0.0f);
    __syncthreads();
    float hv = b2[lane];
    #pragma unroll 8
    for (int j = 0; j < 64; j++) hv = fmaf(ts[w][j], w2[j * 64 + lane], hv);
    hs[w][lane] = hv;
    ws[WS_H + row * 64 + lane] = hv;
    __syncthreads();
    float qv = bq[lane], kv = bk[lane], mv = bm[lane];
    #pragma unroll 4
    for (int j = 0; j < 64; j++) {
        const float hj = hs[w][j];
        qv = fmaf(hj, wq[j * 64 + lane], qv);
        kv = fmaf(hj, wk[j * 64 + lane], kv);
        mv = fmaf(hj, wm[j * 64 + lane], mv);
    }
    u16* wu = (u16*)ws;
    wu[WU_QB + row * 64 + lane] = f2bf(qv * qscale);
    wu[WU_KB + row * 64 + lane] = f2bf(kv);
    wu[WU_MB + row * 64 + lane] = f2bf(mv);
    if (lane == 0) {
        ws[WS_ST + row]  = f2;
        ws[WS_SBI + row] = f2 * coef;
        ws[WS_DEN + row] = 0.0f;                    // zero atomic target
    }
}

// ---------------- Kernel B2: pack Q/K/M into MFMA-fragment order ----------------
// For each 32-row block b, emit fragments laid out so a wave's operand load is
// ONE coalesced dwordx4 (lane l -> 16 contiguous bytes):
//   QP/KP frag(b, s, lane) = X'[b*32 + (l&31)][s*16 + (l>>5)*8 + 0..7]
// where X' is 80-dim: dims 0..63 = q(scaled)/k, dim 64 = sbi[q]/st[k], 65..79=0
// (folds the stateful-bias outer product into the GEMM as a rank-1 dim).
//   MP frag(b, s2, hb, lane) = M^T[hb*32+(l&31)][b*32 + s2*16 + (l>>5)*8 + 0..7]
__global__ __launch_bounds__(256) void pack_k(float* __restrict__ ws) {
    const int b = blockIdx.x;             // 0..255
    const int tid = threadIdx.x;
    const int w = tid >> 6, lane = tid & 63;
    const int hi = lane >> 5, l31 = lane & 31;
    u16* wu = (u16*)ws;
    const u16* qb = wu + WU_QB;
    const u16* kb = wu + WU_KB;
    const u16* mb = wu + WU_MB;

    for (int s = w; s < 5; s += 4) {
        uint4 vq, vk;
        if (s < 4) {
            vq = *(const uint4*)&qb[(size_t)(b * 32 + l31) * 64 + s * 16 + hi * 8];
            vk = *(const uint4*)&kb[(size_t)(b * 32 + l31) * 64 + s * 16 + hi * 8];
        } else {
            vq = make_uint4(0, 0, 0, 0);
            vk = make_uint4(0, 0, 0, 0);
            if (hi == 0) {   // elem 0 of the hi=0 half = dim 64
                vq.x = (u32)f2bf(ws[WS_SBI + b * 32 + l31]);
                vk.x = (u32)f2bf(ws[WS_ST  + b * 32 + l31]);
            }
        }
        *(uint4*)&wu[WU_QP + ((size_t)(b * 5 + s) * 64 + lane) * 8] = vq;
        *(uint4*)&wu[WU_KP + ((size_t)(b * 5 + s) * 64 + lane) * 8] = vk;
    }
    {
        const int s2 = w >> 1, hb = w & 1;
        const int h = hb * 32 + l31;
        u16 e[8];
        #pragma unroll
        for (int j = 0; j < 8; j++)
            e[j] = mb[(size_t)(b * 32 + s2 * 16 + hi * 8 + j) * 64 + h];
        *(uint4*)&wu[WU_MP + ((size_t)(b * 4 + s2 * 2 + hb) * 64 + lane) * 8] =
            *(uint4*)&e[0];
    }
}

// ---------------- Kernel C: LDS-free, barrier-free packed-fragment attention ----------------
// 4 waves / 256 threads; wave owns 32 q-rows; block covers 128 q x 256 k. ZERO
// LDS, ZERO __syncthreads: all MFMA operands are single coalesced dwordx4 loads
// from the L2-resident packed arrays; occupancy is VGPR-bound (launch_bounds
// (256,3) -> 12 waves/CU in 3 independent streams) and no wait ever drains the
// load queues. S^T = mfma(K', Q') over 5 slices (d=80: dim 64 carries the
// stateful-bias fold) so each lane holds P for one q-row: adj is 4x f32x4 along
// the lane's own row (2-step register prefetch), den is ONE register, and P
// turns into the PV A-fragment with 8 shfl_xor(32) + selects (R5-proven).
// Split partials land via fp32 atomics into the 2 MB LLC-resident agg buffer.
__global__ __launch_bounds__(256, 3) void attn_k(const float* __restrict__ adj,
                                                 float* __restrict__ ws)
{
    const int rb = blockIdx.x, sp = blockIdx.y;
    const int i0 = rb * 128, j0 = sp * CPS;
    const int tid = threadIdx.x;
    const int w = tid >> 6, lane = tid & 63;
    const int hi = lane >> 5, l31 = lane & 31;

    const u16* wu = (const u16*)ws;
    const u16* QP = wu + WU_QP;
    const u16* KP = wu + WU_KP;
    const u16* MP = wu + WU_MP;

    const int q0 = i0 + w * 32;
    const int qb32 = q0 >> 5;

    // Q fragments (loop-invariant): one coalesced 1KB load per slice
    bf16x8 qf[5];
    #pragma unroll
    for (int s = 0; s < 5; s++)
        qf[s] = *(const bf16x8*)&QP[((size_t)(qb32 * 5 + s) * 64 + lane) * 8];

    f32x16 acc[2];
    #pragma unroll
    for (int hb = 0; hb < 2; hb++)
        #pragma unroll
        for (int i = 0; i < 16; i++) acc[hb][i] = 0.0f;
    float den = 0.0f;

    // adj: lane's own q-row, 16 floats per step in 4x f32x4; 2-deep prefetch
    const float* adjr = adj + (size_t)(q0 + l31) * N;
    f32x4 av[4], avn[4];
    #pragma unroll
    for (int c2 = 0; c2 < 4; c2++) {
        av[c2]  = *(const f32x4*)&adjr[j0 + c2 * 8 + hi * 4];
        avn[c2] = *(const f32x4*)&adjr[j0 + 32 + c2 * 8 + hi * 4];
    }

    #pragma unroll
    for (int s = 0; s < NSTEP; s++) {
        const int kb = (j0 >> 5) + s;

        // issue step s+2's adj (clamped; nothing ever drains these)
        const int pl = (s + 2 < NSTEP) ? j0 + s * 32 + 64 : j0 + s * 32;
        f32x4 a2[4];
        #pragma unroll
        for (int c2 = 0; c2 < 4; c2++)
            a2[c2] = *(const f32x4*)&adjr[pl + c2 * 8 + hi * 4];

        // S^T: D[k][q] over d=80 (5 packed slices; dim 64 = sb fold)
        f32x16 d;
        #pragma unroll
        for (int i = 0; i < 16; i++) d[i] = 0.0f;
        __builtin_amdgcn_s_setprio(1);
        #pragma unroll
        for (int sl = 0; sl < 5; sl++) {
            const bf16x8 kf = *(const bf16x8*)
                &KP[((size_t)(kb * 5 + sl) * 64 + lane) * 8];
            d = __builtin_amdgcn_mfma_f32_32x32x16_bf16(kf, qf[sl], d, 0, 0, 0);
        }
        __builtin_amdgcn_s_setprio(0);

        // epilogue: reg (4*c2+rr) holds S^T[k = rr + 8*c2 + 4*hi][q = l31]
        u32 wlo[4], whi[4];
        #pragma unroll
        for (int c2 = 0; c2 < 4; c2++) {
            const f32x4 a4 = av[c2];
            const float p0 = a4[0] * __expf(d[c2 * 4 + 0]);
            const float p1 = a4[1] * __expf(d[c2 * 4 + 1]);
            const float p2 = a4[2] * __expf(d[c2 * 4 + 2]);
            const float p3 = a4[3] * __expf(d[c2 * 4 + 3]);
            den += (p0 + p1) + (p2 + p3);
            wlo[c2] = pk2(p0, p1);   // k = 8*c2+4*hi+0,1
            whi[c2] = pk2(p2, p3);   // k = 8*c2+4*hi+2,3
        }

        // P -> PV A-fragment: lane needs P[q=l31][k = s2*16 + hi*8 + 0..7]
        bf16x8 pa[2];
        #pragma unroll
        for (int s2 = 0; s2 < 2; s2++) {
            const u32 xl0 = (u32)__shfl_xor((int)wlo[2 * s2],     32, 64);
            const u32 xh0 = (u32)__shfl_xor((int)whi[2 * s2],     32, 64);
            const u32 xl1 = (u32)__shfl_xor((int)wlo[2 * s2 + 1], 32, 64);
            const u32 xh1 = (u32)__shfl_xor((int)whi[2 * s2 + 1], 32, 64);
            const u32 f0 = hi ? xl1 : wlo[2 * s2];
            const u32 f1 = hi ? xh1 : whi[2 * s2];
            const u32 f2 = hi ? wlo[2 * s2 + 1] : xl0;
            const u32 f3 = hi ? whi[2 * s2 + 1] : xh0;
            pa[s2] = mk8(f0, f1, f2, f3);
        }

        // PV: acc[hb] += P(32q x 32k) @ M(32k x 32h), M frags coalesced
        __builtin_amdgcn_s_setprio(1);
        #pragma unroll
        for (int s2 = 0; s2 < 2; s2++) {
            #pragma unroll
            for (int hb = 0; hb < 2; hb++) {
                const bf16x8 mf = *(const bf16x8*)
                    &MP[((size_t)(kb * 4 + s2 * 2 + hb) * 64 + lane) * 8];
                acc[hb] = __builtin_amdgcn_mfma_f32_32x32x16_bf16(pa[s2], mf, acc[hb], 0, 0, 0);
            }
        }
        __builtin_amdgcn_s_setprio(0);

        // rotate the adj pipeline
        #pragma unroll
        for (int c2 = 0; c2 < 4; c2++) { av[c2] = avn[c2]; avn[c2] = a2[c2]; }
    }

    // denominator: lane halves cover complementary k-sets for the same q-row
    den += __shfl_xor(den, 32, 64);
    if (hi == 0) unsafeAtomicAdd(&ws[WS_DEN + q0 + l31], den);

    // agg partials: lane = h-col, reg = q-row
    float* aggp = ws + WS_AGG;
    #pragma unroll
    for (int hb = 0; hb < 2; hb++) {
        #pragma unroll
        for (int r = 0; r < 16; r++) {
            const int qv = (r & 3) + 8 * (r >> 2) + 4 * hi;
            unsafeAtomicAdd(&aggp[(size_t)(q0 + qv) * 64 + hb * 32 + l31],
                            acc[hb][r]);
        }
    }
}

// ---------------- Kernel D: combine + LayerNorm + final MLP ----------------
__global__ __launch_bounds__(256) void final_k(
    const float* __restrict__ sa, const float* __restrict__ ln_g,
    const float* __restrict__ ln_b,
    const float* __restrict__ wa1, const float* __restrict__ ba1,
    const float* __restrict__ wa2, const float* __restrict__ ba2,
    const float* __restrict__ ws, float* __restrict__ out)
{
    const int w = threadIdx.x >> 6, lane = threadIdx.x & 63;
    const int row = blockIdx.x * 4 + w;
    __shared__ float es[4][64], hs2[4][64];
    const float a = ws[WS_AGG + (size_t)row * 64 + lane];
    const float d = ws[WS_DEN + row];
    const float z = ws[WS_H + row * 64 + lane] + a / d;
    float mu = z;
    for (int off = 32; off; off >>= 1) mu += __shfl_xor(mu, off, 64);
    mu *= (1.0f / 64.0f);
    const float zc = z - mu;
    float var = zc * zc;
    for (int off = 32; off; off >>= 1) var += __shfl_xor(var, off, 64);
    var *= (1.0f / 64.0f);
    const float emb = zc * rsqrtf(var + EPSV) * ln_g[lane] + ln_b[lane];
    es[w][lane] = emb;
    __syncthreads();
    const float sa0 = sa[row * 2], sa1 = sa[row * 2 + 1];
    float hv = ba1[lane];
    #pragma unroll 8
    for (int c = 0; c < 64; c++) hv = fmaf(es[w][c], wa1[c * 64 + lane], hv);
    hv = fmaf(sa0, wa1[64 * 64 + lane], hv);
    hv = fmaf(sa1, wa1[65 * 64 + lane], hv);
    hs2[w][lane] = fmaxf(hv, 0.0f);
    __syncthreads();
    if (lane < 3) {
        float o = ba2[lane];
        for (int u = 0; u < 64; u++) o = fmaf(hs2[w][u], wa2[u * 3 + lane], o);
        out[row * 3 + lane] = o;
    }
}

extern "C" void kernel_launch(void* const* d_in, const int* in_sizes, int n_in,
                              void* d_out, int out_size, void* d_ws, size_t ws_size,
                              hipStream_t stream)
{
    const float* nf  = (const float*)d_in[0];
    const float* adj = (const float*)d_in[1];
    const float* tc  = (const float*)d_in[2];
    const float* sa  = (const float*)d_in[3];
    const float* w1  = (const float*)d_in[4];
    const float* b1  = (const float*)d_in[5];
    const float* w2  = (const float*)d_in[6];
    const float* b2  = (const float*)d_in[7];
    const float* wq  = (const float*)d_in[8];
    const float* bq  = (const float*)d_in[9];
    const float* wk  = (const float*)d_in[10];
    const float* bk  = (const float*)d_in[11];
    const float* wg  = (const float*)d_in[12];
    const float* bg  = (const float*)d_in[13];
    const float* sb  = (const float*)d_in[14];
    const float* wm  = (const float*)d_in[15];
    const float* bm  = (const float*)d_in[16];
    const float* lng = (const float*)d_in[17];
    const float* lnb = (const float*)d_in[18];
    const float* wa1 = (const float*)d_in[19];
    const float* ba1 = (const float*)d_in[20];
    const float* wa2 = (const float*)d_in[21];
    const float* ba2 = (const float*)d_in[22];
    float* ws  = (float*)d_ws;
    float* out = (float*)d_out;

    prep_k<<<1, 64, 0, stream>>>(tc, wg, bg, sb, ws + WS_SCAL);
    embed_k<<<N / 4, 256, 0, stream>>>(nf, tc, w1, b1, w2, b2, wq, bq, wk, bk,
                                       wm, bm, ws);
    pack_k<<<N / 32, 256, 0, stream>>>(ws);
    attn_k<<<dim3(N / 128, NSPLIT), 256, 0, stream>>>(adj, ws);
    final_k<<<N / 4, 256, 0, stream>>>(sa, lng, lnb, wa1, ba1, wa2, ba2, ws, out);
}

// Round 10
// 450.616 us; speedup vs baseline: 1.0751x; 1.0751x over previous
//
#include <hip/hip_runtime.h>
#include <hip/hip_bf16.h>
#include <math.h>

#define N 8192
#define EPSV 1e-05f
#define NSPLIT 32
#define CPS (N / NSPLIT)    // 256 columns per split
#define NSTEP (CPS / 32)    // 8 steps of 32 cols

typedef short bf16x8 __attribute__((ext_vector_type(8)));
typedef float f32x4 __attribute__((ext_vector_type(4)));
typedef float f32x16 __attribute__((ext_vector_type(16)));
typedef unsigned short u16;
typedef unsigned int u32;

// ---- float workspace layout ----
#define WS_SCAL 0
#define WS_H    64                        // N*64 fp32
#define WS_ST   (WS_H + N * 64)           // N
#define WS_SBI  (WS_ST + N)               // N
#define WS_DEN  (WS_SBI + N)              // N      (atomic-accumulated)
#define WS_AGG  (WS_DEN + N)              // N*64   (atomic-accumulated, 2 MB: LLC-resident)
#define WS_F_END (WS_AGG + N * 64)
// ---- u16 (bf16) region, offsets in u16 units from (u16*)ws ----
#define WU_BASE (WS_F_END * 2)
#define WU_QB (WU_BASE)                   // N*64
#define WU_KB (WU_BASE + N * 64)          // N*64
#define WU_MB (WU_BASE + 2 * N * 64)      // N*64 (row-major, transposed later)
#define WU_MT (WU_BASE + 3 * N * 64)      // 64*N

static __device__ __forceinline__ u16 f2bf(float f) {
    __hip_bfloat16 h = __float2bfloat16(f);
    return *(u16*)&h;
}

// ---------------- Kernel A: scalar prep ----------------
__global__ void prep_k(const float* __restrict__ tc, const float* __restrict__ wg,
                       const float* __restrict__ bg, const float* __restrict__ sbias,
                       float* __restrict__ scal) {
    int j = threadIdx.x;  // 64 threads
    float v = tc[0] * wg[j] + tc[1] * wg[64 + j] + bg[j];
    float g = 1.0f / (1.0f + __expf(-v));
    for (int off = 32; off; off >>= 1) g += __shfl_xor(g, off, 64);
    if (j == 0) {
        scal[0] = 0.125f * (g * (1.0f / 64.0f));   // qscale (gate mean + 1/sqrt(64) folded)
        scal[1] = sbias[0] * (1.0f - tc[0]);        // coef
    }
}

// ---------------- Kernel B: embed (h fp32; q,k,m bf16; st, sbi) ----------------
// Also zero-inits the atomic accumulation buffers (agg, den) for its rows.
__global__ __launch_bounds__(256) void embed_k(
    const float* __restrict__ nf, const float* __restrict__ tc,
    const float* __restrict__ w1, const float* __restrict__ b1,
    const float* __restrict__ w2, const float* __restrict__ b2,
    const float* __restrict__ wq, const float* __restrict__ bq,
    const float* __restrict__ wk, const float* __restrict__ bk,
    const float* __restrict__ wm, const float* __restrict__ bm,
    float* __restrict__ ws)
{
    const int w = threadIdx.x >> 6, lane = threadIdx.x & 63;
    const int row = blockIdx.x * 4 + w;
    __shared__ float ts[4][64], hs[4][64];
    const float qscale = ws[WS_SCAL + 0];
    const float coef   = ws[WS_SCAL + 1];
    const float f0 = nf[row * 3], f1 = nf[row * 3 + 1], f2 = nf[row * 3 + 2];
    const float t0 = tc[0], t1 = tc[1];
    ws[WS_AGG + (size_t)row * 64 + lane] = 0.0f;    // zero atomic target
    float v = b1[lane];
    v = fmaf(f0, w1[lane], v);
    v = fmaf(f1, w1[64 + lane], v);
    v = fmaf(f2, w1[128 + lane], v);
    v = fmaf(t0, w1[192 + lane], v);
    v = fmaf(t1, w1[256 + lane], v);
    ts[w][lane] = fmaxf(v, 0.0f);
    __syncthreads();
    float hv = b2[lane];
    #pragma unroll 8
    for (int j = 0; j < 64; j++) hv = fmaf(ts[w][j], w2[j * 64 + lane], hv);
    hs[w][lane] = hv;
    ws[WS_H + row * 64 + lane] = hv;
    __syncthreads();
    float qv = bq[lane], kv = bk[lane], mv = bm[lane];
    #pragma unroll 4
    for (int j = 0; j < 64; j++) {
        const float hj = hs[w][j];
        qv = fmaf(hj, wq[j * 64 + lane], qv);
        kv = fmaf(hj, wk[j * 64 + lane], kv);
        mv = fmaf(hj, wm[j * 64 + lane], mv);
    }
    u16* wu = (u16*)ws;
    wu[WU_QB + row * 64 + lane] = f2bf(qv * qscale);
    wu[WU_KB + row * 64 + lane] = f2bf(kv);
    wu[WU_MB + row * 64 + lane] = f2bf(mv);
    if (lane == 0) {
        ws[WS_ST + row]  = f2;
        ws[WS_SBI + row] = f2 * coef;
        ws[WS_DEN + row] = 0.0f;                    // zero atomic target
    }
}

// ---------------- Kernel B2: transpose M (bf16) ----------------
__global__ __launch_bounds__(256) void transp_k(float* __restrict__ ws) {
    const u16* mb = (const u16*)ws + WU_MB;
    u16* mt = (u16*)ws + WU_MT;
    __shared__ __align__(16) u16 tile[64][72];
    const int i0 = blockIdx.x * 64;
    const int t = threadIdx.x;
    {
        const int r = t >> 2, cb = (t & 3) * 16;
        *(uint4*)&tile[r][cb]     = *(const uint4*)&mb[(size_t)(i0 + r) * 64 + cb];
        *(uint4*)&tile[r][cb + 8] = *(const uint4*)&mb[(size_t)(i0 + r) * 64 + cb + 8];
    }
    __syncthreads();
    const int c = t >> 2, rb = (t & 3) * 16;
    u16 tmp[16];
    #pragma unroll
    for (int i = 0; i < 16; i++) tmp[i] = tile[rb + i][c];
    *(uint4*)&mt[(size_t)c * N + i0 + rb]     = *(uint4*)&tmp[0];
    *(uint4*)&mt[(size_t)c * N + i0 + rb + 8] = *(uint4*)&tmp[8];
}

// ---------------- Kernel C: split-resident MFMA attention, 4-deep adj pipeline ----------------
// R8 base: K-panel (256x64) and M-panel (64x256) staged ONCE into swizzled LDS
// with a single __syncthreads; zero barriers in the k-loop. NEW: the adjacency
// stream uses a 4-deep register pipeline (fully unrolled, static ring indices):
// each step consumes batch (s&3), then immediately re-issues it for step s+4.
// Steady state ~48 outstanding dword loads/wave (~12 KB in flight) x 8 waves/CU
// -> the HBM stream stays saturated instead of the ~15% issue-duty that pinned
// every prior variant at ~1.2 TB/s. Everything else identical to R8.
__global__ __launch_bounds__(256, 2) void attn_k(const float* __restrict__ adj,
                                                 float* __restrict__ ws)
{
    const int rb = blockIdx.x, sp = blockIdx.y;
    const int i0 = rb * 128, j0 = sp * CPS;
    const int tid = threadIdx.x;
    const int w = tid >> 6, lane = tid & 63;
    const int hi = lane >> 5, l31 = lane & 31;

    __shared__ __align__(16) u16 ks[256 * 64];    // 32 KB swizzled [k=256][d=64]
    __shared__ __align__(16) u16 ms[64 * 256];    // 32 KB swizzled [h=64][k=256]
    __shared__ __align__(16) u16 ps[4][32][40];   // 10 KB per-wave P strips
    __shared__ float stl[CPS];                    //  1 KB

    const u16* qb  = (const u16*)ws + WU_QB;
    const u16* kbp = (const u16*)ws + WU_KB;
    const u16* mtp = (const u16*)ws + WU_MT;

    // ---- prologue: stage the whole split (once) ----
    #pragma unroll
    for (int i = 0; i < 8; i++) {
        const int id = tid + 256 * i;        // 0..2047
        const int r = id >> 3, c = id & 7;   // k-row, 16B chunk (8 per 128B row)
        const int off = r * 64 + (((c * 16) ^ ((r & 7) << 4)) >> 1);
        *(uint4*)&ks[off] = *(const uint4*)&kbp[(size_t)(j0 + r) * 64 + c * 8];
    }
    #pragma unroll
    for (int i = 0; i < 8; i++) {
        const int id = tid + 256 * i;        // 0..2047
        const int r = id >> 5, c = id & 31;  // h-row, 16B chunk (32 per 512B row)
        const int off = r * 256 + (((c * 16) ^ ((r & 7) << 4)) >> 1);
        *(uint4*)&ms[off] = *(const uint4*)&mtp[(size_t)r * N + j0 + c * 8];
    }
    stl[tid] = ws[WS_ST + j0 + tid];
    __syncthreads();                          // the ONLY block-wide barrier

    const int q0 = i0 + w * 32;

    // Q A-fragments: lane = q-row l31, 8 d-elems, hi selects d-half
    const u16* qr = qb + (size_t)(q0 + l31) * 64;
    bf16x8 qf[4];
    #pragma unroll
    for (int s = 0; s < 4; s++) qf[s] = *(const bf16x8*)&qr[s * 16 + hi * 8];

    // per-reg q-row bias coefs (loop-invariant)
    float sbir[16];
    #pragma unroll
    for (int r = 0; r < 16; r++) {
        const int qv = (r & 3) + 8 * (r >> 2) + 4 * hi;
        sbir[r] = ws[WS_SBI + q0 + qv];
    }

    f32x16 acc[2];
    #pragma unroll
    for (int hb = 0; hb < 2; hb++)
        #pragma unroll
        for (int i = 0; i < 16; i++) acc[hb][i] = 0.0f;
    float den[16];
    #pragma unroll
    for (int r = 0; r < 16; r++) den[r] = 0.0f;

    // per-lane adj base: row block (q0 + 4*hi), column j0 + l31
    const float* adjh = adj + (size_t)(q0 + 4 * hi) * N + j0 + l31;

    // ---- 4-deep coalesced adj pipeline: ab[d] holds step (s: s&3==d) ----
    float ab[4][16];
    #pragma unroll
    for (int d = 0; d < 4; d++) {
        #pragma unroll
        for (int r = 0; r < 16; r++) {
            const int cr = (r & 3) + 8 * (r >> 2);
            ab[d][r] = adjh[(size_t)cr * N + d * 32];
        }
    }

    #pragma unroll
    for (int s = 0; s < NSTEP; s++) {         // FULL unroll: ring indices static
        const int loc = s * 32;               // k-local base of this step
        const int cur = s & 3;

        // S: D[q][k] over d=64 (4 x mfma32x32x16, A=Q, B=K from swizzled LDS)
        f32x16 d;
        #pragma unroll
        for (int i = 0; i < 16; i++) d[i] = 0.0f;
        __builtin_amdgcn_s_setprio(1);
        #pragma unroll
        for (int s4 = 0; s4 < 4; s4++) {
            const int R = loc + l31;
            const bf16x8 kf = *(const bf16x8*)
                &ks[R * 64 + (((s4 * 32 + hi * 16) ^ ((R & 7) << 4)) >> 1)];
            d = __builtin_amdgcn_mfma_f32_32x32x16_bf16(qf[s4], kf, d, 0, 0, 0);
        }
        __builtin_amdgcn_s_setprio(0);

        // epilogue: reg r holds S[q0 + qv][k = j0 + loc + l31]; consumes ab[cur]
        const float stc = stl[loc + l31];
        #pragma unroll
        for (int r = 0; r < 16; r++) {
            const int qv = (r & 3) + 8 * (r >> 2) + 4 * hi;
            const float p = ab[cur][r] * __expf(fmaf(sbir[r], stc, d[r]));
            den[r] += p;
            ps[w][qv][l31] = f2bf(p);         // P[q-local][k-local]
        }

        // re-issue ab[cur] for step s+4 (stays in flight ~3.5 steps; no WAR)
        if (s + 4 < NSTEP) {
            #pragma unroll
            for (int r = 0; r < 16; r++) {
                const int cr = (r & 3) + 8 * (r >> 2);
                ab[cur][r] = adjh[(size_t)cr * N + loc + 128];
            }
        }

        // PV: A = P from ps (lane = q-row), B = M from swizzled ms (lane = h)
        __builtin_amdgcn_s_setprio(1);
        #pragma unroll
        for (int s2 = 0; s2 < 2; s2++) {
            const bf16x8 pa = *(const bf16x8*)&ps[w][l31][s2 * 16 + hi * 8];
            #pragma unroll
            for (int hb = 0; hb < 2; hb++) {
                const int R2 = hb * 32 + l31;
                const bf16x8 mf = *(const bf16x8*)
                    &ms[R2 * 256 +
                        (((loc * 2 + s2 * 32 + hi * 16) ^ ((R2 & 7) << 4)) >> 1)];
                acc[hb] = __builtin_amdgcn_mfma_f32_32x32x16_bf16(pa, mf, acc[hb], 0, 0, 0);
            }
        }
        __builtin_amdgcn_s_setprio(0);
    }

    // denominator: sum over k = reduce across the 32 lanes of each half
    #pragma unroll
    for (int r = 0; r < 16; r++) {
        float dv = den[r];
        dv += __shfl_xor(dv, 1, 64);
        dv += __shfl_xor(dv, 2, 64);
        dv += __shfl_xor(dv, 4, 64);
        dv += __shfl_xor(dv, 8, 64);
        dv += __shfl_xor(dv, 16, 64);
        den[r] = dv;
    }
    if (l31 == 0) {
        #pragma unroll
        for (int r = 0; r < 16; r++) {
            const int qv = (r & 3) + 8 * (r >> 2) + 4 * hi;
            unsafeAtomicAdd(&ws[WS_DEN + q0 + qv], den[r]);
        }
    }

    // agg partials: lane = h-col, reg = q-row
    float* aggp = ws + WS_AGG;
    #pragma unroll
    for (int hb = 0; hb < 2; hb++) {
        #pragma unroll
        for (int r = 0; r < 16; r++) {
            const int qv = (r & 3) + 8 * (r >> 2) + 4 * hi;
            unsafeAtomicAdd(&aggp[(size_t)(q0 + qv) * 64 + hb * 32 + l31],
                            acc[hb][r]);
        }
    }
}

// ---------------- Kernel D: combine + LayerNorm + final MLP ----------------
__global__ __launch_bounds__(256) void final_k(
    const float* __restrict__ sa, const float* __restrict__ ln_g,
    const float* __restrict__ ln_b,
    const float* __restrict__ wa1, const float* __restrict__ ba1,
    const float* __restrict__ wa2, const float* __restrict__ ba2,
    const float* __restrict__ ws, float* __restrict__ out)
{
    const int w = threadIdx.x >> 6, lane = threadIdx.x & 63;
    const int row = blockIdx.x * 4 + w;
    __shared__ float es[4][64], hs2[4][64];
    const float a = ws[WS_AGG + (size_t)row * 64 + lane];
    const float d = ws[WS_DEN + row];
    const float z = ws[WS_H + row * 64 + lane] + a / d;
    float mu = z;
    for (int off = 32; off; off >>= 1) mu += __shfl_xor(mu, off, 64);
    mu *= (1.0f / 64.0f);
    const float zc = z - mu;
    float var = zc * zc;
    for (int off = 32; off; off >>= 1) var += __shfl_xor(var, off, 64);
    var *= (1.0f / 64.0f);
    const float emb = zc * rsqrtf(var + EPSV) * ln_g[lane] + ln_b[lane];
    es[w][lane] = emb;
    __syncthreads();
    const float sa0 = sa[row * 2], sa1 = sa[row * 2 + 1];
    float hv = ba1[lane];
    #pragma unroll 8
    for (int c = 0; c < 64; c++) hv = fmaf(es[w][c], wa1[c * 64 + lane], hv);
    hv = fmaf(sa0, wa1[64 * 64 + lane], hv);
    hv = fmaf(sa1, wa1[65 * 64 + lane], hv);
    hs2[w][lane] = fmaxf(hv, 0.0f);
    __syncthreads();
    if (lane < 3) {
        float o = ba2[lane];
        for (int u = 0; u < 64; u++) o = fmaf(hs2[w][u], wa2[u * 3 + lane], o);
        out[row * 3 + lane] = o;
    }
}

extern "C" void kernel_launch(void* const* d_in, const int* in_sizes, int n_in,
                              void* d_out, int out_size, void* d_ws, size_t ws_size,
                              hipStream_t stream)
{
    const float* nf  = (const float*)d_in[0];
    const float* adj = (const float*)d_in[1];
    const float* tc  = (const float*)d_in[2];
    const float* sa  = (const float*)d_in[3];
    const float* w1  = (const float*)d_in[4];
    const float* b1  = (const float*)d_in[5];
    const float* w2  = (const float*)d_in[6];
    const float* b2  = (const float*)d_in[7];
    const float* wq  = (const float*)d_in[8];
    const float* bq  = (const float*)d_in[9];
    const float* wk  = (const float*)d_in[10];
    const float* bk  = (const float*)d_in[11];
    const float* wg  = (const float*)d_in[12];
    const float* bg  = (const float*)d_in[13];
    const float* sb  = (const float*)d_in[14];
    const float* wm  = (const float*)d_in[15];
    const float* bm  = (const float*)d_in[16];
    const float* lng = (const float*)d_in[17];
    const float* lnb = (const float*)d_in[18];
    const float* wa1 = (const float*)d_in[19];
    const float* ba1 = (const float*)d_in[20];
    const float* wa2 = (const float*)d_in[21];
    const float* ba2 = (const float*)d_in[22];
    float* ws  = (float*)d_ws;
    float* out = (float*)d_out;

    prep_k<<<1, 64, 0, stream>>>(tc, wg, bg, sb, ws + WS_SCAL);
    embed_k<<<N / 4, 256, 0, stream>>>(nf, tc, w1, b1, w2, b2, wq, bq, wk, bk,
                                       wm, bm, ws);
    transp_k<<<N / 64, 256, 0, stream>>>(ws);
    attn_k<<<dim3(N / 128, NSPLIT), 256, 0, stream>>>(adj, ws);
    final_k<<<N / 4, 256, 0, stream>>>(sa, lng, lnb, wa1, ba1, wa2, ba2, ws, out);
}